// Round 11
// baseline (439.379 us; speedup 1.0000x reference)
//
#include <hip/hip_runtime.h>

#define N_NODES 50000
#define N_EDGES 800000
#define DIM 128
#define KTOT 256        // [agg | h] concatenated along k
#define N_GRAPHS 64
#define BUCKET_CAP 64
#define LSTR 264        // LDS A-tile row stride in bf16 (+8 pad -> conflict-free b128)
#define PSLOTS 8        // per-block LDS pool slots (block spans <=2 graphs normally)

typedef __attribute__((ext_vector_type(8))) short bf16x8;
typedef __attribute__((ext_vector_type(16))) float f32x16;

__device__ __forceinline__ float bf2f(unsigned int u16) {
    return __uint_as_float(u16 << 16);
}
__device__ __forceinline__ unsigned short f2bf(float f) {
    unsigned int v = __float_as_uint(f);
    unsigned int r = (v + 0x7fffu + ((v >> 16) & 1u)) >> 16;   // RNE
    return (unsigned short)r;
}

// ---------- setup: one kernel zeros cnt/pool/done, casts x and W ----------
__global__ void cast_all_kernel(const float* __restrict__ x, ushort* __restrict__ xb,
                                int* __restrict__ cnt,
                                const float* __restrict__ Wl0, const float* __restrict__ Wr0,
                                const float* __restrict__ Wl1, const float* __restrict__ Wr1,
                                const float* __restrict__ Wl2, const float* __restrict__ Wr2,
                                ushort* __restrict__ wb, float* __restrict__ pool,
                                int* __restrict__ done) {
    int i = blockIdx.x * blockDim.x + threadIdx.x;
    if (i == 0) *done = 0;
    if (i < N_NODES) cnt[i] = 0;
    if (i < N_GRAPHS * DIM) pool[i] = 0.f;
    if (i < 3 * DIM * KTOT) {   // W cast: [128 j][256 k], k<128 = Wl, k>=128 = Wr
        int l = i >> 15;
        int r = i & 32767;
        int j = r >> 8, k = r & 255;
        const float* Wl = (l == 0) ? Wl0 : (l == 1) ? Wl1 : Wl2;
        const float* Wr = (l == 0) ? Wr0 : (l == 1) ? Wr1 : Wr2;
        float v = (k < DIM) ? Wl[j * DIM + k] : Wr[j * DIM + k - DIM];
        wb[i] = f2bf(v);
    }
    if (i < N_NODES * DIM / 4) {
        float4 v = ((const float4*)x)[i];
        ushort4 o;
        o.x = f2bf(v.x); o.y = f2bf(v.y); o.z = f2bf(v.z); o.w = f2bf(v.w);
        ((ushort4*)xb)[i] = o;
    }
}

// ushort buckets: src < 50000 fits 16 bits (R6-proven; CSR+scan regressed in R7).
__global__ void fill_kernel(const int* __restrict__ src, const int* __restrict__ dst,
                            int* __restrict__ cnt, ushort* __restrict__ bucket) {
    int e = blockIdx.x * blockDim.x + threadIdx.x;
    if (e >= N_EDGES) return;
    int d = dst[e];
    int pos = atomicAdd(&cnt[d], 1);
    if (pos < BUCKET_CAP) bucket[d * BUCKET_CAP + pos] = (ushort)src[e];
}

// ---------- pull aggregation: ONE ROW PER WAVE (12500 blocks — max TLP) ----------
// Half-wave h takes even/odd edges; lane owns 4 cols (8 B). 16-edge unroll = 8
// independent uint2 loads in flight per half-wave (deg~16 -> one iteration).
__global__ __launch_bounds__(256) void gather_kernel(
    const ushort* __restrict__ X, const int* __restrict__ cnt,
    const ushort* __restrict__ bucket, ushort* __restrict__ agg) {
    int n = (blockIdx.x * blockDim.x + threadIdx.x) >> 6;
    int lane = threadIdx.x & 63;
    if (n >= N_NODES) return;
    int c = cnt[n];
    int cl = c < BUCKET_CAP ? c : BUCKET_CAP;
    const ushort* b = bucket + (size_t)n * BUCKET_CAP;
    const int half = lane >> 5, lcol = lane & 31;
    float a0 = 0.f, a1 = 0.f, a2 = 0.f, a3 = 0.f;
    int e = half;
    for (; e + 14 < cl; e += 16) {
        int s0 = b[e],      s1 = b[e + 2],  s2 = b[e + 4],  s3 = b[e + 6];
        int s4 = b[e + 8],  s5 = b[e + 10], s6 = b[e + 12], s7 = b[e + 14];
        uint2 u0 = *(const uint2*)(X + (size_t)s0 * DIM + lcol * 4);
        uint2 u1 = *(const uint2*)(X + (size_t)s1 * DIM + lcol * 4);
        uint2 u2 = *(const uint2*)(X + (size_t)s2 * DIM + lcol * 4);
        uint2 u3 = *(const uint2*)(X + (size_t)s3 * DIM + lcol * 4);
        uint2 u4 = *(const uint2*)(X + (size_t)s4 * DIM + lcol * 4);
        uint2 u5 = *(const uint2*)(X + (size_t)s5 * DIM + lcol * 4);
        uint2 u6 = *(const uint2*)(X + (size_t)s6 * DIM + lcol * 4);
        uint2 u7 = *(const uint2*)(X + (size_t)s7 * DIM + lcol * 4);
        a0 += bf2f(u0.x & 0xffff) + bf2f(u1.x & 0xffff) + bf2f(u2.x & 0xffff) + bf2f(u3.x & 0xffff)
            + bf2f(u4.x & 0xffff) + bf2f(u5.x & 0xffff) + bf2f(u6.x & 0xffff) + bf2f(u7.x & 0xffff);
        a1 += bf2f(u0.x >> 16)    + bf2f(u1.x >> 16)    + bf2f(u2.x >> 16)    + bf2f(u3.x >> 16)
            + bf2f(u4.x >> 16)    + bf2f(u5.x >> 16)    + bf2f(u6.x >> 16)    + bf2f(u7.x >> 16);
        a2 += bf2f(u0.y & 0xffff) + bf2f(u1.y & 0xffff) + bf2f(u2.y & 0xffff) + bf2f(u3.y & 0xffff)
            + bf2f(u4.y & 0xffff) + bf2f(u5.y & 0xffff) + bf2f(u6.y & 0xffff) + bf2f(u7.y & 0xffff);
        a3 += bf2f(u0.y >> 16)    + bf2f(u1.y >> 16)    + bf2f(u2.y >> 16)    + bf2f(u3.y >> 16)
            + bf2f(u4.y >> 16)    + bf2f(u5.y >> 16)    + bf2f(u6.y >> 16)    + bf2f(u7.y >> 16);
    }
    for (; e < cl; e += 2) {
        uint2 u0 = *(const uint2*)(X + (size_t)b[e] * DIM + lcol * 4);
        a0 += bf2f(u0.x & 0xffff);
        a1 += bf2f(u0.x >> 16);
        a2 += bf2f(u0.y & 0xffff);
        a3 += bf2f(u0.y >> 16);
    }
    a0 += __shfl_xor(a0, 32);
    a1 += __shfl_xor(a1, 32);
    a2 += __shfl_xor(a2, 32);
    a3 += __shfl_xor(a3, 32);
    if (half == 0) {
        float inv = 1.0f / (float)(c > 0 ? c : 1);
        uint2 o;
        o.x = ((unsigned int)f2bf(a1 * inv) << 16) | f2bf(a0 * inv);
        o.y = ((unsigned int)f2bf(a3 * inv) << 16) | f2bf(a2 * inv);
        *(uint2*)(agg + (size_t)n * DIM + lcol * 4) = o;
    }
}

// ---------- MFMA layer: out[50000x128] = [agg|h][50000x256] . W[128x256]^T ----------
__global__ __launch_bounds__(512, 4) void layer_mfma(
    const ushort* __restrict__ aggb, const ushort* __restrict__ hb,
    const ushort* __restrict__ wb, const float* __restrict__ bl,
    ushort* __restrict__ outb, int relu)
{
    __shared__ ushort sA[64 * LSTR];
    const int tid = threadIdx.x;
    const int lane = tid & 63, w = tid >> 6;
    const int mh = w & 1, jq = w >> 1;
    const int n0 = blockIdx.x * 64;

    bf16x8 bw[16];
    {
        const ushort* wp = wb + (size_t)(jq * 32 + (lane & 31)) * KTOT + (lane >> 5) * 8;
        #pragma unroll
        for (int kt = 0; kt < 16; ++kt)
            bw[kt] = *(const bf16x8*)(wp + kt * 16);
    }

    #pragma unroll
    for (int it = 0; it < 4; ++it) {
        int ci = tid + it * 512;
        int row = ci >> 5;
        int k8 = (ci & 31) * 8;
        int gn = n0 + row;
        bf16x8 v = (bf16x8){0,0,0,0,0,0,0,0};
        if (gn < N_NODES) {
            const ushort* p = (k8 < DIM) ? (aggb + (size_t)gn * DIM + k8)
                                         : (hb + (size_t)gn * DIM + (k8 - DIM));
            v = *(const bf16x8*)p;
        }
        *(bf16x8*)(&sA[row * LSTR + k8]) = v;
    }
    __syncthreads();

    f32x16 acc = {};
    const int arow = mh * 32 + (lane & 31);
    const int akoff = (lane >> 5) * 8;
    #pragma unroll
    for (int kt = 0; kt < 16; ++kt) {
        bf16x8 a = *(const bf16x8*)(&sA[arow * LSTR + kt * 16 + akoff]);
        acc = __builtin_amdgcn_mfma_f32_32x32x16_bf16(a, bw[kt], acc, 0, 0, 0);
    }

    // C/D map: col=lane&31, row=(reg&3)+8*(reg>>2)+4*(lane>>5)  [m74/m101]
    const int col = lane & 31;
    const int j = jq * 32 + col;
    const float bias = bl[j];
    #pragma unroll
    for (int r = 0; r < 16; ++r) {
        int row = (r & 3) + 8 * (r >> 2) + 4 * (lane >> 5);
        int gn = n0 + mh * 32 + row;
        if (gn < N_NODES) {
            float v = acc[r] + bias;
            if (relu) v = fmaxf(v, 0.f);
            outb[(size_t)gn * DIM + j] = f2bf(v);
        }
    }
}

// ---------- layer 3 + pool fused: no h3 write; per-graph sums -> pool; last
// block divides by counts and writes out (done-counter). ----------
__global__ __launch_bounds__(512, 4) void layer_final(
    const ushort* __restrict__ aggb, const ushort* __restrict__ hb,
    const ushort* __restrict__ wb, const float* __restrict__ bl,
    const int* __restrict__ batch, float* __restrict__ pool,
    int* __restrict__ done, float* __restrict__ out)
{
    __shared__ ushort sA[64 * LSTR];
    __shared__ float sPool[PSLOTS * DIM];
    __shared__ int sBatch[64];
    __shared__ int lastFlag;
    const int tid = threadIdx.x;
    const int lane = tid & 63, w = tid >> 6;
    const int mh = w & 1, jq = w >> 1;
    const int n0 = blockIdx.x * 64;

    for (int idx = tid; idx < PSLOTS * DIM; idx += 512) sPool[idx] = 0.f;
    if (tid < 64) {
        int gn = n0 + tid;
        sBatch[tid] = batch[gn < N_NODES ? gn : (N_NODES - 1)];
    }

    bf16x8 bw[16];
    {
        const ushort* wp = wb + (size_t)(jq * 32 + (lane & 31)) * KTOT + (lane >> 5) * 8;
        #pragma unroll
        for (int kt = 0; kt < 16; ++kt)
            bw[kt] = *(const bf16x8*)(wp + kt * 16);
    }

    #pragma unroll
    for (int it = 0; it < 4; ++it) {
        int ci = tid + it * 512;
        int row = ci >> 5;
        int k8 = (ci & 31) * 8;
        int gn = n0 + row;
        bf16x8 v = (bf16x8){0,0,0,0,0,0,0,0};
        if (gn < N_NODES) {
            const ushort* p = (k8 < DIM) ? (aggb + (size_t)gn * DIM + k8)
                                         : (hb + (size_t)gn * DIM + (k8 - DIM));
            v = *(const bf16x8*)p;
        }
        *(bf16x8*)(&sA[row * LSTR + k8]) = v;
    }
    __syncthreads();

    f32x16 acc = {};
    const int arow = mh * 32 + (lane & 31);
    const int akoff = (lane >> 5) * 8;
    #pragma unroll
    for (int kt = 0; kt < 16; ++kt) {
        bf16x8 a = *(const bf16x8*)(&sA[arow * LSTR + kt * 16 + akoff]);
        acc = __builtin_amdgcn_mfma_f32_32x32x16_bf16(a, bw[kt], acc, 0, 0, 0);
    }

    // Epilogue: per-thread per-graph partial sums (<=2 graphs per 32-row half;
    // 3rd+ graph falls back to a direct global atomic).
    const int col = lane & 31;
    const int j = jq * 32 + col;
    const float bias = bl[j];
    int ga = -1, gb = -1;
    float sa = 0.f, sb = 0.f;
    #pragma unroll
    for (int r = 0; r < 16; ++r) {
        int row = (r & 3) + 8 * (r >> 2) + 4 * (lane >> 5);
        int gn = n0 + mh * 32 + row;
        if (gn < N_NODES) {
            float v = acc[r] + bias;   // last layer: no relu
            int g = sBatch[mh * 32 + row];
            if (g == ga) sa += v;
            else if (ga < 0) { ga = g; sa = v; }
            else if (g == gb) sb += v;
            else if (gb < 0) { gb = g; sb = v; }
            else unsafeAtomicAdd(&pool[g * DIM + j], v);
        }
    }
    const int g0 = sBatch[0];
    if (ga >= 0) {
        int gl = ga - g0;
        if (gl >= 0 && gl < PSLOTS) atomicAdd(&sPool[gl * DIM + j], sa);
        else unsafeAtomicAdd(&pool[ga * DIM + j], sa);
    }
    if (gb >= 0) {
        int gl = gb - g0;
        if (gl >= 0 && gl < PSLOTS) atomicAdd(&sPool[gl * DIM + j], sb);
        else unsafeAtomicAdd(&pool[gb * DIM + j], sb);
    }
    __syncthreads();
    for (int idx = tid; idx < PSLOTS * DIM; idx += 512) {
        float v = sPool[idx];
        int g = g0 + (idx >> 7);
        if (v != 0.f && g < N_GRAPHS)
            unsafeAtomicAdd(&pool[g * DIM + (idx & (DIM - 1))], v);
    }
    __syncthreads();   // compiler drains vmcnt before barrier -> flush atomics issued
    if (tid == 0) {
        __threadfence();
        int old = atomicAdd(done, 1);
        lastFlag = (old == (int)gridDim.x - 1);
    }
    __syncthreads();
    if (lastFlag) {
        for (int idx = tid; idx < N_GRAPHS * DIM; idx += 512) {
            int g = idx >> 7;
            int lo = 0, hi = N_NODES;
            while (lo < hi) { int m = (lo + hi) >> 1; if (batch[m] < g) lo = m + 1; else hi = m; }
            int start = lo;
            lo = start; hi = N_NODES;
            while (lo < hi) { int m = (lo + hi) >> 1; if (batch[m] < g + 1) lo = m + 1; else hi = m; }
            int cntg = lo - start;
            float s = __hip_atomic_load(&pool[idx], __ATOMIC_RELAXED, __HIP_MEMORY_SCOPE_AGENT);
            out[idx] = s / (float)(cntg > 0 ? cntg : 1);
        }
    }
}

extern "C" void kernel_launch(void* const* d_in, const int* in_sizes, int n_in,
                              void* d_out, int out_size, void* d_ws, size_t ws_size,
                              hipStream_t stream) {
    const float* x    = (const float*)d_in[0];
    const int*   ei   = (const int*)d_in[1];
    const int*   src  = ei;
    const int*   dst  = ei + N_EDGES;
    const int*   batch = (const int*)d_in[2];
    const float* Wl0 = (const float*)d_in[3];
    const float* bl0 = (const float*)d_in[4];
    const float* Wr0 = (const float*)d_in[5];
    const float* Wl1 = (const float*)d_in[6];
    const float* bl1 = (const float*)d_in[7];
    const float* Wr1 = (const float*)d_in[8];
    const float* Wl2 = (const float*)d_in[9];
    const float* bl2 = (const float*)d_in[10];
    const float* Wr2 = (const float*)d_in[11];
    float* out = (float*)d_out;

    int*    cnt    = (int*)d_ws;                               // 65536 ints
    int*    done   = cnt + 65536;                              // 64 ints
    ushort* bucket = (ushort*)(done + 64);                     // 3.2M ushorts
    ushort* xb     = bucket + (size_t)N_NODES * BUCKET_CAP;
    ushort* aggb   = xb + (size_t)N_NODES * DIM;
    ushort* h1b    = aggb + (size_t)N_NODES * DIM;
    ushort* h2b    = h1b + (size_t)N_NODES * DIM;
    ushort* wb     = h2b + (size_t)N_NODES * DIM;              // 3 * 32768 bf16
    float*  pool   = (float*)(wb + 3 * DIM * KTOT);            // 8192 floats

    cast_all_kernel<<<(N_NODES * DIM / 4 + 255) / 256, 256, 0, stream>>>(
        x, xb, cnt, Wl0, Wr0, Wl1, Wr1, Wl2, Wr2, wb, pool, done);
    fill_kernel<<<(N_EDGES + 255) / 256, 256, 0, stream>>>(src, dst, cnt, bucket);

    const int ggrid = (N_NODES * 64 + 255) / 256;   // one wave per node
    const int lgrid = (N_NODES + 63) / 64;

    gather_kernel<<<ggrid, 256, 0, stream>>>(xb, cnt, bucket, aggb);
    layer_mfma<<<lgrid, 512, 0, stream>>>(aggb, xb, wb,          bl0, h1b, 1);
    gather_kernel<<<ggrid, 256, 0, stream>>>(h1b, cnt, bucket, aggb);
    layer_mfma<<<lgrid, 512, 0, stream>>>(aggb, h1b, wb + 32768, bl1, h2b, 1);
    gather_kernel<<<ggrid, 256, 0, stream>>>(h2b, cnt, bucket, aggb);
    layer_final<<<lgrid, 512, 0, stream>>>(aggb, h2b, wb + 65536, bl2, batch, pool, done, out);
}